// Round 1
// baseline (624.236 us; speedup 1.0000x reference)
//
#include <hip/hip_runtime.h>

#define NV 320
#define NB 32
#define NL 2048
#define ND 1024
#define CH 32            // l-chunks per batch
#define CL (NL / CH)     // 64 positions per chunk

// Kernel A: per-batch histogram -> per-position prob -> per-batch sum.
// One block per batch, 256 threads.
__global__ __launch_bounds__(256) void vq_weights_kernel(
    const int* __restrict__ vq_indices,   // (B, L, 2) int32
    const int* __restrict__ lengths,      // (B,) int32
    float* __restrict__ prob,             // (B, L) ws
    float* __restrict__ sums)             // (B,)  ws
{
    __shared__ int cx[NV];
    __shared__ int cy[NV];
    __shared__ float wave_sums[4];

    const int b = blockIdx.x;
    const int t = threadIdx.x;

    for (int i = t; i < NV; i += 256) { cx[i] = 0; cy[i] = 0; }
    __syncthreads();

    const int2* idx = (const int2*)(vq_indices) + (size_t)b * NL;
    // histogram over ALL L positions (reference counts unmasked)
    for (int l = t; l < NL; l += 256) {
        int2 v = idx[l];
        atomicAdd(&cx[v.x], 1);
        atomicAdd(&cy[v.y], 1);
    }
    __syncthreads();

    const int len = lengths[b];
    float local = 0.f;
    for (int l = t; l < NL; l += 256) {
        int2 v = idx[l];
        float p = 0.f;
        if (l < len) p = 1.0f / (float)(cx[v.x] + cy[v.y]);
        prob[(size_t)b * NL + l] = p;
        local += p;
    }
    // wave64 reduce, then cross-wave via LDS
    for (int off = 32; off > 0; off >>= 1)
        local += __shfl_down(local, off, 64);
    if ((t & 63) == 0) wave_sums[t >> 6] = local;
    __syncthreads();
    if (t == 0)
        sums[b] = wave_sums[0] + wave_sums[1] + wave_sums[2] + wave_sums[3];
}

// Kernel B: out[b,d] += (1/sum_b) * sum_{l in chunk} prob[b,l] * feat[b,1,l,d]
// grid = (CH, B), block = 256 threads, thread t owns float4 at d = 4t.
__global__ __launch_bounds__(256) void vq_pool_kernel(
    const float* __restrict__ feature,    // (B, 2, L, D) f32
    const int* __restrict__ lengths,
    const float* __restrict__ prob,
    const float* __restrict__ sums,
    float* __restrict__ out)              // (B, D) f32, pre-zeroed
{
    const int c = blockIdx.x;
    const int b = blockIdx.y;
    const int len = lengths[b];
    const int l0 = c * CL;
    const int l1 = min(l0 + CL, len);
    if (l0 >= l1) return;   // chunk entirely masked; prob there is 0 anyway

    const int t = threadIdx.x;

    __shared__ float wloc[CL];
    if (t < CL) wloc[t] = prob[(size_t)b * NL + l0 + t];
    __syncthreads();

    // feat slice [b, n=1]: base offset (b*2 + 1) * L * D
    const float4* f4 = (const float4*)(feature + ((size_t)b * 2 + 1) * (size_t)NL * ND);

    float4 acc = {0.f, 0.f, 0.f, 0.f};
    #pragma unroll 4
    for (int l = l0; l < l1; ++l) {
        float w = wloc[l - l0];                 // LDS broadcast (conflict-free)
        float4 v = f4[(size_t)l * (ND / 4) + t]; // coalesced 16B/lane
        acc.x += w * v.x;
        acc.y += w * v.y;
        acc.z += w * v.z;
        acc.w += w * v.w;
    }

    const float inv = 1.0f / sums[b];
    float* o = out + (size_t)b * ND + t * 4;
    atomicAdd(o + 0, acc.x * inv);
    atomicAdd(o + 1, acc.y * inv);
    atomicAdd(o + 2, acc.z * inv);
    atomicAdd(o + 3, acc.w * inv);
}

extern "C" void kernel_launch(void* const* d_in, const int* in_sizes, int n_in,
                              void* d_out, int out_size, void* d_ws, size_t ws_size,
                              hipStream_t stream) {
    const float* feature = (const float*)d_in[0];   // (B, 2, L, D) f32
    const int*   lengths = (const int*)d_in[1];     // (B,) int
    const int*   vq      = (const int*)d_in[2];     // (B, L, 2) int
    float* out = (float*)d_out;

    float* prob = (float*)d_ws;          // B*L floats
    float* sums = prob + (size_t)NB * NL; // B floats

    // d_out is poisoned 0xAA before every launch — zero it for the atomics.
    hipMemsetAsync(d_out, 0, (size_t)out_size * sizeof(float), stream);

    vq_weights_kernel<<<NB, 256, 0, stream>>>(vq, lengths, prob, sums);
    vq_pool_kernel<<<dim3(CH, NB), 256, 0, stream>>>(feature, lengths, prob, sums, out);
}